// Round 1
// baseline (5180.216 us; speedup 1.0000x reference)
//
#include <hip/hip_runtime.h>

// LightGCN encoder: 3-layer propagation over fixed graph, batch gather.
// Sizes are compile-time constants matching the reference generator.
#define N_USERS 100000
#define N_ITEMS 50000
#define N_NODES 150000
#define DIM 64
#define NUM_LAYERS 3
#define BATCH 4096

// Build x = concat(user_emb, item_emb) into node buffer (float4-vectorized).
__global__ void lgcn_init_x(const float* __restrict__ ue,
                            const float* __restrict__ ie,
                            float* __restrict__ x) {
    long long t = (long long)blockIdx.x * blockDim.x + threadIdx.x; // float4 idx
    const long long nU4 = (long long)N_USERS * (DIM / 4);
    const long long nT4 = (long long)N_NODES * (DIM / 4);
    if (t >= nT4) return;
    float4 v = (t < nU4) ? ((const float4*)ue)[t] : ((const float4*)ie)[t - nU4];
    ((float4*)x)[t] = v;
}

// Push-scatter: for each edge e, hn[dst[e]] += h[src[e]] * w[e].
// 16 lanes per edge, one float4 per lane (row = 64 floats = 16 float4).
__global__ void lgcn_scatter(const float* __restrict__ h,
                             float* __restrict__ hn,
                             const int* __restrict__ src,
                             const int* __restrict__ dst,
                             const float* __restrict__ w,
                             int E) {
    int t = blockIdx.x * blockDim.x + threadIdx.x;
    int e = t >> 4;
    if (e >= E) return;
    int lane = t & 15;
    int s = src[e];
    int d = dst[e];
    float we = w[e];
    float4 v = ((const float4*)(h + (long long)s * DIM))[lane];
    float* o = hn + (long long)d * DIM + lane * 4;
    atomicAdd(o + 0, v.x * we);
    atomicAdd(o + 1, v.y * we);
    atomicAdd(o + 2, v.z * we);
    atomicAdd(o + 3, v.w * we);
}

// Gather the batch rows from node buffer h, scaled by 1/4, into out.
// Layout: out[0 .. BATCH*64) = users, then items. accumulate=0 writes, 1 adds.
__global__ void lgcn_gather_out(const float* __restrict__ h,
                                const int* __restrict__ uid,
                                const int* __restrict__ iid,
                                float* __restrict__ out,
                                int accumulate) {
    int t = blockIdx.x * blockDim.x + threadIdx.x; // [0, 2*BATCH*16)
    const int half = BATCH * (DIM / 4);            // 65536
    if (t >= 2 * half) return;
    int isItem = (t >= half);
    int local = t - (isItem ? half : 0);
    int b = local >> 4;
    int lane = local & 15;
    int node = isItem ? (N_USERS + iid[b]) : uid[b];
    float4 v = ((const float4*)(h + (long long)node * DIM))[lane];
    const float q = 0.25f;
    float4* o = ((float4*)out) + t;
    if (accumulate) {
        float4 c = *o;
        c.x += v.x * q; c.y += v.y * q; c.z += v.z * q; c.w += v.w * q;
        *o = c;
    } else {
        *o = make_float4(v.x * q, v.y * q, v.z * q, v.w * q);
    }
}

extern "C" void kernel_launch(void* const* d_in, const int* in_sizes, int n_in,
                              void* d_out, int out_size, void* d_ws, size_t ws_size,
                              hipStream_t stream) {
    const float* ue  = (const float*)d_in[0];   // [N_USERS, 64]
    const float* ie  = (const float*)d_in[1];   // [N_ITEMS, 64]
    const float* w   = (const float*)d_in[2];   // [E]
    const int*   ei  = (const int*)d_in[3];     // [2, E] row-major
    const int*   uid = (const int*)d_in[4];     // [BATCH]
    const int*   iid = (const int*)d_in[5];     // [BATCH]
    float* out = (float*)d_out;

    const int E = in_sizes[2];                  // 2,000,000
    const int* src = ei;
    const int* dst = ei + E;

    const size_t nodeBytes = (size_t)N_NODES * DIM * sizeof(float); // 38.4 MB
    float* hA = (float*)d_ws;
    float* hB = (float*)((char*)d_ws + nodeBytes);

    // Layer 0: x into hA, out = x[ids]/4.
    {
        int nt = N_NODES * (DIM / 4);
        lgcn_init_x<<<(nt + 255) / 256, 256, 0, stream>>>(ue, ie, hA);
    }
    lgcn_gather_out<<<(2 * BATCH * (DIM / 4) + 255) / 256, 256, 0, stream>>>(
        hA, uid, iid, out, 0);

    float* h  = hA;
    float* hn = hB;
    for (int l = 0; l < NUM_LAYERS; ++l) {
        hipMemsetAsync(hn, 0, nodeBytes, stream);
        long long nt = (long long)E * 16;
        lgcn_scatter<<<(int)((nt + 255) / 256), 256, 0, stream>>>(h, hn, src, dst, w, E);
        lgcn_gather_out<<<(2 * BATCH * (DIM / 4) + 255) / 256, 256, 0, stream>>>(
            hn, uid, iid, out, 1);
        float* tmp = h; h = hn; hn = tmp;
    }
}

// Round 2
// 591.554 us; speedup vs baseline: 8.7570x; 8.7570x over previous
//
#include <hip/hip_runtime.h>

// LightGCN encoder on MI355X.
// Round 2: replace fp32 atomic push-scatter (128M atomics/layer, 1.69 ms each)
// with per-call CSR build + pull-gather (1 coalesced store per node row).
#define N_USERS 100000
#define N_NODES 150000
#define DIM 64
#define BATCH 4096
#define CHUNK 1024   // scan chunk per block

// --- CSR build -------------------------------------------------------------

__global__ void lgcn_hist(const int* __restrict__ dst, int* __restrict__ deg, int E) {
    int e = blockIdx.x * blockDim.x + threadIdx.x;
    if (e < E) atomicAdd(&deg[dst[e]], 1);
}

// Per-block exclusive scan of CHUNK degrees; block total -> partials[blk].
__global__ void lgcn_scan1(const int* __restrict__ deg, int* __restrict__ rp,
                           int* __restrict__ partials) {
    __shared__ int bufA[CHUNK], bufB[CHUNK];
    int blk = blockIdx.x;
    int base = blk * CHUNK;
    for (int i = threadIdx.x; i < CHUNK; i += blockDim.x) {
        int g = base + i;
        bufA[i] = (g < N_NODES) ? deg[g] : 0;
    }
    __syncthreads();
    int* cur = bufA; int* nxt = bufB;
    for (int off = 1; off < CHUNK; off <<= 1) {
        for (int i = threadIdx.x; i < CHUNK; i += blockDim.x)
            nxt[i] = (i >= off) ? cur[i] + cur[i - off] : cur[i];
        __syncthreads();
        int* t = cur; cur = nxt; nxt = t;
    }
    for (int i = threadIdx.x; i < CHUNK; i += blockDim.x) {
        int g = base + i;
        if (g < N_NODES) rp[g] = (i == 0) ? 0 : cur[i - 1];
    }
    if (threadIdx.x == 0) partials[blk] = cur[CHUNK - 1];
}

// Single-block exclusive scan of the P block totals (P <= CHUNK).
__global__ void lgcn_scan2(int* __restrict__ partials, int P) {
    __shared__ int bufA[CHUNK], bufB[CHUNK];
    for (int i = threadIdx.x; i < CHUNK; i += blockDim.x)
        bufA[i] = (i < P) ? partials[i] : 0;
    __syncthreads();
    int* cur = bufA; int* nxt = bufB;
    for (int off = 1; off < CHUNK; off <<= 1) {
        for (int i = threadIdx.x; i < CHUNK; i += blockDim.x)
            nxt[i] = (i >= off) ? cur[i] + cur[i - off] : cur[i];
        __syncthreads();
        int* t = cur; cur = nxt; nxt = t;
    }
    for (int i = threadIdx.x; i < P; i += blockDim.x)
        partials[i] = (i == 0) ? 0 : cur[i - 1];
}

// Add scanned block offsets; init fill cursors; write rp[N_NODES] = E.
__global__ void lgcn_scan3(int* __restrict__ rp, const int* __restrict__ partials,
                           int* __restrict__ cursor, int E) {
    int g = blockIdx.x * blockDim.x + threadIdx.x;
    if (g < N_NODES) {
        int v = rp[g] + partials[g >> 10];
        rp[g] = v;
        cursor[g] = v;
    } else if (g == N_NODES) {
        rp[g] = E;
    }
}

// Slot each edge into its dst's CSR segment: packed = {src, bits(w)}.
__global__ void lgcn_fill(const int* __restrict__ src, const int* __restrict__ dst,
                          const float* __restrict__ w, int* __restrict__ cursor,
                          int2* __restrict__ packed, int E) {
    int e = blockIdx.x * blockDim.x + threadIdx.x;
    if (e >= E) return;
    int d = dst[e];
    int pos = atomicAdd(&cursor[d], 1);
    int2 v;
    v.x = src[e];
    v.y = __float_as_int(w[e]);
    packed[pos] = v;
}

// --- Propagation -----------------------------------------------------------

// Pull-gather: hn[n] = sum over in-edges (src,w) of w * h[src].
// 16 lanes per node, one float4 per lane. Source rows come from a split
// address space (pu for node<N_USERS, pi otherwise) so layer 1 can read the
// original embeddings without materializing x; for unified buffers pass
// pu = h, pi = h + N_USERS*DIM.
__global__ void lgcn_pull(const float* __restrict__ pu, const float* __restrict__ pi,
                          const int* __restrict__ rp, const int2* __restrict__ packed,
                          float* __restrict__ hn) {
    int t = blockIdx.x * blockDim.x + threadIdx.x;
    int n = t >> 4;
    if (n >= N_NODES) return;
    int lane = t & 15;
    int p0 = rp[n], p1 = rp[n + 1];
    float4 acc = make_float4(0.f, 0.f, 0.f, 0.f);
    for (int p = p0; p < p1; ++p) {
        int2 ew = packed[p];
        int s = ew.x;
        float we = __int_as_float(ew.y);
        const float* base = (s < N_USERS) ? (pu + (long long)s * DIM)
                                          : (pi + (long long)(s - N_USERS) * DIM);
        float4 v = ((const float4*)base)[lane];
        acc.x += v.x * we; acc.y += v.y * we;
        acc.z += v.z * we; acc.w += v.w * we;
    }
    ((float4*)(hn + (long long)n * DIM))[lane] = acc;
}

// out[b] (+)= 0.25 * row[ids[b]]; users first, then items.
__global__ void lgcn_gather_out(const float* __restrict__ pu, const float* __restrict__ pi,
                                const int* __restrict__ uid, const int* __restrict__ iid,
                                float* __restrict__ out, int accumulate) {
    int t = blockIdx.x * blockDim.x + threadIdx.x; // [0, 2*BATCH*16)
    const int half = BATCH * (DIM / 4);            // 65536
    if (t >= 2 * half) return;
    int isItem = (t >= half);
    int local = t - (isItem ? half : 0);
    int b = local >> 4;
    int lane = local & 15;
    const float* base = isItem ? (pi + (long long)iid[b] * DIM)
                               : (pu + (long long)uid[b] * DIM);
    float4 v = ((const float4*)base)[lane];
    const float q = 0.25f;
    float4* o = ((float4*)out) + t;
    if (accumulate) {
        float4 c = *o;
        c.x += v.x * q; c.y += v.y * q; c.z += v.z * q; c.w += v.w * q;
        *o = c;
    } else {
        *o = make_float4(v.x * q, v.y * q, v.z * q, v.w * q);
    }
}

// --- Launch ----------------------------------------------------------------

extern "C" void kernel_launch(void* const* d_in, const int* in_sizes, int n_in,
                              void* d_out, int out_size, void* d_ws, size_t ws_size,
                              hipStream_t stream) {
    const float* ue  = (const float*)d_in[0];   // [N_USERS, 64]
    const float* ie  = (const float*)d_in[1];   // [N_ITEMS, 64]
    const float* w   = (const float*)d_in[2];   // [E]
    const int*   ei  = (const int*)d_in[3];     // [2, E] row-major
    const int*   uid = (const int*)d_in[4];     // [BATCH]
    const int*   iid = (const int*)d_in[5];     // [BATCH]
    float* out = (float*)d_out;

    const int E = in_sizes[2];                  // 2,000,000
    const int* src = ei;
    const int* dst = ei + E;

    // Workspace carve-up (256-B aligned regions), ~94 MB total.
    const size_t nodeBytes = (size_t)N_NODES * DIM * sizeof(float); // 38.4 MB
    char* p = (char*)d_ws;
    size_t off = 0;
    auto carve = [&](size_t bytes) -> char* {
        char* r = p + off;
        off += (bytes + 255) & ~(size_t)255;
        return r;
    };
    float* hA      = (float*)carve(nodeBytes);
    float* hB      = (float*)carve(nodeBytes);
    int*   rp      = (int*)carve((size_t)(N_NODES + 1) * sizeof(int));
    int*   deg     = (int*)carve((size_t)N_NODES * sizeof(int));
    int*   cursor  = (int*)carve((size_t)N_NODES * sizeof(int));
    int*   partials= (int*)carve((size_t)CHUNK * sizeof(int));
    int2*  packed  = (int2*)carve((size_t)E * sizeof(int2));
    (void)ws_size;

    const int nScanBlks = (N_NODES + CHUNK - 1) / CHUNK;  // 147

    // 1) CSR build.
    hipMemsetAsync(deg, 0, (size_t)N_NODES * sizeof(int), stream);
    lgcn_hist<<<(E + 255) / 256, 256, 0, stream>>>(dst, deg, E);
    lgcn_scan1<<<nScanBlks, 256, 0, stream>>>(deg, rp, partials);
    lgcn_scan2<<<1, 256, 0, stream>>>(partials, nScanBlks);
    lgcn_scan3<<<(N_NODES + 1 + 255) / 256, 256, 0, stream>>>(rp, partials, cursor, E);
    lgcn_fill<<<(E + 255) / 256, 256, 0, stream>>>(src, dst, w, cursor, packed, E);

    // 2) Layer 0 contribution: out = x[ids]/4 straight from embeddings.
    const int gatherGrid = (2 * BATCH * (DIM / 4) + 255) / 256;
    lgcn_gather_out<<<gatherGrid, 256, 0, stream>>>(ue, ie, uid, iid, out, 0);

    // 3) Three pull layers, accumulating batch rows into out each time.
    const int pullGrid = (N_NODES * 16 + 255) / 256;
    const float* cu = ue;          // current layer source, user part
    const float* ci = ie;          // current layer source, item part
    float* bufs[2] = { hA, hB };
    for (int l = 0; l < 3; ++l) {
        float* hn = bufs[l & 1];
        lgcn_pull<<<pullGrid, 256, 0, stream>>>(cu, ci, rp, packed, hn);
        lgcn_gather_out<<<gatherGrid, 256, 0, stream>>>(
            hn, hn + (size_t)N_USERS * DIM, uid, iid, out, 1);
        cu = hn;
        ci = hn + (size_t)N_USERS * DIM;
    }
}